// Round 2
// baseline (585.121 us; speedup 1.0000x reference)
//
#include <hip/hip_runtime.h>
#include <hip/hip_bf16.h>
#include <stdint.h>
#include <stddef.h>

// Problem constants
#define BB 4
#define LL 2048
#define KNB 30
#define IND 128
#define OUTD 400
#define NGEMM 800           // 2*OUTD: [T | U] combined GEMM width
#define NQ (BB*LL)          // 8192 queries / rows
#define OUT_EIDX_OFF 98304000  // 4*2048*30*400

typedef short short8 __attribute__((ext_vector_type(8)));
typedef float f32x4 __attribute__((ext_vector_type(4)));

__device__ __forceinline__ unsigned short f2b(float f) {
    unsigned int u = __float_as_uint(f);
    unsigned int r = (u + 0x7FFFu + ((u >> 16) & 1u)) >> 16;  // RNE
    return (unsigned short)r;
}
__device__ __forceinline__ float b2f(unsigned short u) {
    return __uint_as_float(((unsigned int)u) << 16);
}

// ---------------------------------------------------------------------------
// K1: convert V -> bf16 (Vb), build transposed+concatenated W -> bf16 (Wt).
// (Xpl extraction removed: knn reads X directly -- X is 393KB, L2-resident,
//  and this removes a serial producer->consumer dependency.)
// ---------------------------------------------------------------------------
__global__ __launch_bounds__(256) void convert_kernel(
    const float* __restrict__ V, const float* __restrict__ W,
    unsigned short* __restrict__ Vb, unsigned short* __restrict__ Wt) {
    int bid = blockIdx.x;
    int t = threadIdx.x;
    if (bid < 1024) {
        // V: 1,048,576 floats, 4 per thread
        int g = bid * 256 + t;
        float4 v = ((const float4*)V)[g];
        ushort4 o;
        o.x = f2b(v.x); o.y = f2b(v.y); o.z = f2b(v.z); o.w = f2b(v.w);
        ((ushort4*)Vb)[g] = o;
    } else {
        // Wt[n][c]: n<400 -> W[c,n]; n>=400 -> W[128+c, n-400]. 102,400 elems.
        int g = (bid - 1024) * 256 + t;
        int n = g >> 7, c = g & 127;
        float f = (n < OUTD) ? W[c * OUTD + n] : W[(IND + c) * OUTD + (n - OUTD)];
        Wt[g] = f2b(f);
    }
}

// ---------------------------------------------------------------------------
// K2: KNN.  One WAVE per query (4 waves/block share the coord tile).
// Exact reference arithmetic (round-to-nearest mul/add/sqrt, no contraction),
// stable tie-break by index via u64 key = (f32bits(D_adjust) << 32) | j.
// Extraction uses DESTRUCTIVE invalidation: extracted slots become ~0ULL,
// so the per-round scan is a pure 3-op u64 min (no removed-bitmap selects).
// All per-lane arrays use compile-time indices only -> registers, no scratch.
// ---------------------------------------------------------------------------
__global__ __launch_bounds__(256) void knn_kernel(
    const float* __restrict__ X, const float* __restrict__ mask,
    int* __restrict__ idx_out, float* __restrict__ eidx_out) {
    __shared__ float4 sc[LL];   // (x, y, z, mask) interleaved: one ds_read_b128/cand

    int t = threadIdx.x;
    int wid = t >> 6, lane = t & 63;
    int q = blockIdx.x * 4 + wid;        // 4 queries per block, same batch b
    int b = q >> 11, l = q & 2047;
    int base = b * LL;

    for (int i = t; i < LL; i += 256) {
        // Xca = X[:, :, 1, :]  ->  floats at m*12 + 3..5.  Cached in L2.
        const float* xp = X + (size_t)(base + i) * 12 + 3;
        float4 c;
        c.x = xp[0];
        c.y = xp[1];
        c.z = xp[2];
        c.w = mask[base + i];
        sc[i] = c;
    }
    __syncthreads();

    float4 qc = sc[l];
    float qx = qc.x, qy = qc.y, qz = qc.z, qm = qc.w;

    // Pass 1: distances + row max (for the mask-adjust term)
    float d[32], m2[32];
    float lmax = -1.0f;
    #pragma unroll
    for (int s = 0; s < 32; s++) {
        int j = lane + 64 * s;
        float4 c = sc[j];
        float dx = __fsub_rn(qx, c.x);
        float dy = __fsub_rn(qy, c.y);
        float dz = __fsub_rn(qz, c.z);
        float d2 = __fadd_rn(__fadd_rn(__fadd_rn(__fmul_rn(dx, dx), __fmul_rn(dy, dy)),
                                       __fmul_rn(dz, dz)), 1e-6f);
        float mm = __fmul_rn(qm, c.w);
        float dd = __fmul_rn(mm, __fsqrt_rn(d2));
        d[s] = dd; m2[s] = mm;
        lmax = fmaxf(lmax, dd);
    }
    #pragma unroll
    for (int off = 1; off < 64; off <<= 1)
        lmax = fmaxf(lmax, __shfl_xor(lmax, off));
    float Dmax = lmax;

    // Pass 2: u64 keys (value<<32 | index) -- ascending sort order == reference
    unsigned long long k64[32];
    #pragma unroll
    for (int s = 0; s < 32; s++) {
        float dadj = __fadd_rn(d[s], __fmul_rn(__fsub_rn(1.0f, m2[s]), Dmax));
        k64[s] = (((unsigned long long)__float_as_uint(dadj)) << 32)
               | (unsigned int)(lane + 64 * s);
    }

    // 30 extraction rounds: 4-chain ILP min scan + wave butterfly min,
    // then the winning lane poisons its extracted slot to ~0ULL.
    unsigned int myj = 0u;
    for (int k = 0; k < KNB; k++) {
        unsigned long long c0 = k64[0], c1 = k64[1], c2 = k64[2], c3 = k64[3];
        #pragma unroll
        for (int s = 4; s < 32; s += 4) {
            c0 = (k64[s]     < c0) ? k64[s]     : c0;
            c1 = (k64[s + 1] < c1) ? k64[s + 1] : c1;
            c2 = (k64[s + 2] < c2) ? k64[s + 2] : c2;
            c3 = (k64[s + 3] < c3) ? k64[s + 3] : c3;
        }
        c0 = (c1 < c0) ? c1 : c0;
        c2 = (c3 < c2) ? c3 : c2;
        unsigned long long lm = (c2 < c0) ? c2 : c0;
        #pragma unroll
        for (int off = 1; off < 64; off <<= 1) {
            unsigned long long o = __shfl_xor(lm, off);
            lm = (o < lm) ? o : lm;
        }
        unsigned int j = (unsigned int)lm;
        if ((j & 63u) == (unsigned int)lane) {
            int slot = (int)(j >> 6);
            #pragma unroll
            for (int s = 0; s < 32; s++)
                if (s == slot) k64[s] = ~0ULL;
        }
        if (lane == k) myj = j;
    }
    size_t qb = (size_t)q * KNB;
    if (lane < KNB) {
        idx_out[qb + lane] = (int)myj;
        eidx_out[qb + lane] = (float)myj;
    }
}

// ---------------------------------------------------------------------------
// K3: TU = Vb(8192x128) @ Wt^T  -> bf16 TU (8192x800).  One wave per 16x16
// tile, K=128 via 4x mfma_f32_16x16x32_bf16.
// ---------------------------------------------------------------------------
__global__ __launch_bounds__(256) void gemm_kernel(
    const unsigned short* __restrict__ Vb, const unsigned short* __restrict__ Wt,
    unsigned short* __restrict__ TU) {
    int wid = threadIdx.x >> 6, lane = threadIdx.x & 63;
    int tile = blockIdx.x * 4 + wid;       // 25600 tiles
    int tm = tile / 50, tn = tile % 50;
    int r16 = lane & 15, quad = lane >> 4;

    const unsigned short* Abase = Vb + (size_t)(tm * 16 + r16) * IND + quad * 8;
    const unsigned short* Bbase = Wt + (size_t)(tn * 16 + r16) * IND + quad * 8;

    f32x4 acc = {0.f, 0.f, 0.f, 0.f};
    #pragma unroll
    for (int kk = 0; kk < IND; kk += 32) {
        short8 a = *(const short8*)(Abase + kk);
        short8 b = *(const short8*)(Bbase + kk);
        acc = __builtin_amdgcn_mfma_f32_16x16x32_bf16(a, b, acc, 0, 0, 0);
    }
    int col = lane & 15;
    #pragma unroll
    for (int r = 0; r < 4; r++) {
        int m = tm * 16 + quad * 4 + r;
        TU[(size_t)m * NGEMM + tn * 16 + col] = f2b(acc[r]);
    }
}

// ---------------------------------------------------------------------------
// K4: epilogue.  TWO waves per (b,l): wave-half h covers k in [15h, 15h+15).
// Per group of 3 k's all 6 gather loads issue before any store (MLP=6);
// idx row preloaded once and distributed via __shfl (no per-iter idx load).
// Output is write-once streaming -> nontemporal stores keep L2 free for the
// heavily-reused TU rows (each U row gathered ~30x).
// NOTE: nontemporal stores use the clang ext_vector f32x4 (HIP float4 is a
// class type the builtin rejects).
// ---------------------------------------------------------------------------
__device__ __forceinline__ f32x4 comb(const float* tt, ushort4 u) {
    f32x4 o;
    o.x = tt[0] + b2f(u.x);
    o.y = tt[1] + b2f(u.y);
    o.z = tt[2] + b2f(u.z);
    o.w = tt[3] + b2f(u.w);
    return o;
}

__global__ __launch_bounds__(256) void epi_kernel(
    const unsigned short* __restrict__ TU, const int* __restrict__ idx,
    const float* __restrict__ bias, float* __restrict__ out) {
    int t = threadIdx.x;
    int wid = t >> 6, lane = t & 63;
    int q = blockIdx.x * 2 + (wid >> 1);   // 2 queries per block
    int half = wid & 1;                    // which 15 of the 30 neighbors
    int b = q >> 11;

    const int* mi = idx + (size_t)q * KNB;
    int jv = (lane < KNB) ? mi[lane] : 0;  // one coalesced preload of all idx
    int i0 = __shfl(jv, 0);
    size_t rowbase = (size_t)(b * LL);
    size_t rowT = (rowbase + i0) * NGEMM;

    float t0[4], t1[4];
    {
        ushort4 u = *(const ushort4*)(TU + rowT + lane * 4);
        float4 bb = *(const float4*)(bias + lane * 4);
        t0[0] = b2f(u.x) + bb.x;
        t0[1] = b2f(u.y) + bb.y;
        t0[2] = b2f(u.z) + bb.z;
        t0[3] = b2f(u.w) + bb.w;
    }
    bool has2 = lane < 36;
    int c2 = lane + 64;
    if (has2) {
        ushort4 u = *(const ushort4*)(TU + rowT + c2 * 4);
        float4 bb = *(const float4*)(bias + c2 * 4);
        t1[0] = b2f(u.x) + bb.x;
        t1[1] = b2f(u.y) + bb.y;
        t1[2] = b2f(u.z) + bb.z;
        t1[3] = b2f(u.w) + bb.w;
    }

    size_t outbase = (size_t)q * KNB * OUTD;
    int kb = half * 15;
    for (int g = 0; g < 5; g++) {
        int k0 = kb + g * 3;
        int j0 = __shfl(jv, k0);
        int j1 = __shfl(jv, k0 + 1);
        int j2 = __shfl(jv, k0 + 2);
        const unsigned short* r0 = TU + (rowbase + j0) * NGEMM + OUTD;
        const unsigned short* r1 = TU + (rowbase + j1) * NGEMM + OUTD;
        const unsigned short* r2 = TU + (rowbase + j2) * NGEMM + OUTD;
        // issue all gathers before any use
        ushort4 a0 = *(const ushort4*)(r0 + lane * 4);
        ushort4 a1 = *(const ushort4*)(r1 + lane * 4);
        ushort4 a2 = *(const ushort4*)(r2 + lane * 4);
        ushort4 b0, b1, b2;
        if (has2) {
            b0 = *(const ushort4*)(r0 + c2 * 4);
            b1 = *(const ushort4*)(r1 + c2 * 4);
            b2 = *(const ushort4*)(r2 + c2 * 4);
        }
        float* o0 = out + outbase + (size_t)(k0    ) * OUTD;
        float* o1 = out + outbase + (size_t)(k0 + 1) * OUTD;
        float* o2 = out + outbase + (size_t)(k0 + 2) * OUTD;
        __builtin_nontemporal_store(comb(t0, a0), (f32x4*)(o0 + lane * 4));
        __builtin_nontemporal_store(comb(t0, a1), (f32x4*)(o1 + lane * 4));
        __builtin_nontemporal_store(comb(t0, a2), (f32x4*)(o2 + lane * 4));
        if (has2) {
            __builtin_nontemporal_store(comb(t1, b0), (f32x4*)(o0 + c2 * 4));
            __builtin_nontemporal_store(comb(t1, b1), (f32x4*)(o1 + c2 * 4));
            __builtin_nontemporal_store(comb(t1, b2), (f32x4*)(o2 + c2 * 4));
        }
    }
}

extern "C" void kernel_launch(void* const* d_in, const int* in_sizes, int n_in,
                              void* d_out, int out_size, void* d_ws, size_t ws_size,
                              hipStream_t stream) {
    const float* X    = (const float*)d_in[0];
    const float* mask = (const float*)d_in[1];
    const float* V    = (const float*)d_in[2];
    const float* W    = (const float*)d_in[3];
    const float* bias = (const float*)d_in[4];
    float* out = (float*)d_out;

    char* ws = (char*)d_ws;
    unsigned short* Vb  = (unsigned short*)(ws);                 // 2,097,152 B
    unsigned short* Wt  = (unsigned short*)(ws + 2097152);       //   204,800 B
    int*            idx = (int*)(ws + 2301952);                  //   983,040 B
    unsigned short* TU  = (unsigned short*)(ws + 3284992);       // 13,107,200 B
    // total ws use: ~15.6 MB

    convert_kernel<<<1424, 256, 0, stream>>>(V, W, Vb, Wt);
    knn_kernel<<<NQ / 4, 256, 0, stream>>>(X, mask, idx, out + OUT_EIDX_OFF);
    gemm_kernel<<<6400, 256, 0, stream>>>(Vb, Wt, TU);
    epi_kernel<<<NQ / 2, 256, 0, stream>>>(TU, idx, bias, out);
}

// Round 3
// 546.793 us; speedup vs baseline: 1.0701x; 1.0701x over previous
//
#include <hip/hip_runtime.h>
#include <hip/hip_bf16.h>
#include <stdint.h>
#include <stddef.h>

// Problem constants
#define BB 4
#define LL 2048
#define KNB 30
#define IND 128
#define OUTD 400
#define NGEMM 800           // 2*OUTD: [T | U] combined GEMM width
#define NQ (BB*LL)          // 8192 queries / rows
#define OUT_EIDX_OFF 98304000  // 4*2048*30*400

typedef short short8 __attribute__((ext_vector_type(8)));
typedef float f32x4 __attribute__((ext_vector_type(4)));

__device__ __forceinline__ unsigned short f2b(float f) {
    unsigned int u = __float_as_uint(f);
    unsigned int r = (u + 0x7FFFu + ((u >> 16) & 1u)) >> 16;  // RNE
    return (unsigned short)r;
}
__device__ __forceinline__ float b2f(unsigned short u) {
    return __uint_as_float(((unsigned int)u) << 16);
}

// ---------------------------------------------------------------------------
// K1: convert V -> bf16 (Vb), build transposed+concatenated W -> bf16 (Wt),
//     extract Xca planes (x,y,z) to compact fp32 buffer (coalesced source
//     for knn staging -- reading X directly in knn was a measured -26us
//     regression: 48B-stride loads amplified 2048x across blocks).
// ---------------------------------------------------------------------------
__global__ __launch_bounds__(256) void convert_kernel(
    const float* __restrict__ V, const float* __restrict__ W,
    const float* __restrict__ X,
    unsigned short* __restrict__ Vb, unsigned short* __restrict__ Wt,
    float* __restrict__ Xpl) {
    int bid = blockIdx.x;
    int t = threadIdx.x;
    if (bid < 1024) {
        // V: 1,048,576 floats, 4 per thread
        int g = bid * 256 + t;
        float4 v = ((const float4*)V)[g];
        ushort4 o;
        o.x = f2b(v.x); o.y = f2b(v.y); o.z = f2b(v.z); o.w = f2b(v.w);
        ((ushort4*)Vb)[g] = o;
    } else if (bid < 1424) {
        // Wt[n][c]: n<400 -> W[c,n]; n>=400 -> W[128+c, n-400]. 102,400 elems.
        int g = (bid - 1024) * 256 + t;
        int n = g >> 7, c = g & 127;
        float f = (n < OUTD) ? W[c * OUTD + n] : W[(IND + c) * OUTD + (n - OUTD)];
        Wt[g] = f2b(f);
    } else {
        // Xca planes: 3 * 8192 elems.  X[(m)*12 + 3 + c]
        int g = (bid - 1424) * 256 + t;   // [0, 24576)
        int c = g >> 13, m = g & 8191;
        Xpl[c * NQ + m] = X[(size_t)m * 12 + 3 + c];
    }
}

// ---------------------------------------------------------------------------
// K2: KNN.  One WAVE per query (4 waves/block share the coord tile).
// Exact reference arithmetic (round-to-nearest mul/add/sqrt, no contraction),
// stable tie-break by index via u64 key = (f32bits(D_adjust) << 32) | j.
// Extraction uses DESTRUCTIVE invalidation of the HIGH WORD only: real keys
// have finite-float high words (< 0x7F800001), so hi=0xFFFFFFFF never wins.
// This is cmp+1 cndmask per slot instead of cmp+2.
// All per-lane arrays use compile-time indices only -> registers, no scratch.
// ---------------------------------------------------------------------------
__global__ __launch_bounds__(256) void knn_kernel(
    const float* __restrict__ Xpl, const float* __restrict__ mask,
    int* __restrict__ idx_out, float* __restrict__ eidx_out) {
    __shared__ float4 sc[LL];   // (x, y, z, mask) interleaved: one ds_read_b128/cand

    int t = threadIdx.x;
    int wid = t >> 6, lane = t & 63;
    int q = blockIdx.x * 4 + wid;        // 4 queries per block, same batch b
    int b = q >> 11, l = q & 2047;
    int base = b * LL;

    for (int i = t; i < LL; i += 256) {
        float4 c;
        c.x = Xpl[base + i];
        c.y = Xpl[NQ + base + i];
        c.z = Xpl[2 * NQ + base + i];
        c.w = mask[base + i];
        sc[i] = c;
    }
    __syncthreads();

    float4 qc = sc[l];
    float qx = qc.x, qy = qc.y, qz = qc.z, qm = qc.w;

    // Pass 1: distances + row max (for the mask-adjust term)
    float d[32], m2[32];
    float lmax = -1.0f;
    #pragma unroll
    for (int s = 0; s < 32; s++) {
        int j = lane + 64 * s;
        float4 c = sc[j];
        float dx = __fsub_rn(qx, c.x);
        float dy = __fsub_rn(qy, c.y);
        float dz = __fsub_rn(qz, c.z);
        float d2 = __fadd_rn(__fadd_rn(__fadd_rn(__fmul_rn(dx, dx), __fmul_rn(dy, dy)),
                                       __fmul_rn(dz, dz)), 1e-6f);
        float mm = __fmul_rn(qm, c.w);
        float dd = __fmul_rn(mm, __fsqrt_rn(d2));
        d[s] = dd; m2[s] = mm;
        lmax = fmaxf(lmax, dd);
    }
    #pragma unroll
    for (int off = 1; off < 64; off <<= 1)
        lmax = fmaxf(lmax, __shfl_xor(lmax, off));
    float Dmax = lmax;

    // Pass 2: u64 keys (value<<32 | index) -- ascending sort order == reference
    unsigned long long k64[32];
    #pragma unroll
    for (int s = 0; s < 32; s++) {
        float dadj = __fadd_rn(d[s], __fmul_rn(__fsub_rn(1.0f, m2[s]), Dmax));
        k64[s] = (((unsigned long long)__float_as_uint(dadj)) << 32)
               | (unsigned int)(lane + 64 * s);
    }

    // 30 extraction rounds: 4-chain ILP min scan + wave butterfly min,
    // then the winning lane poisons its extracted slot's high word.
    unsigned int myj = 0u;
    for (int k = 0; k < KNB; k++) {
        unsigned long long c0 = k64[0], c1 = k64[1], c2 = k64[2], c3 = k64[3];
        #pragma unroll
        for (int s = 4; s < 32; s += 4) {
            c0 = (k64[s]     < c0) ? k64[s]     : c0;
            c1 = (k64[s + 1] < c1) ? k64[s + 1] : c1;
            c2 = (k64[s + 2] < c2) ? k64[s + 2] : c2;
            c3 = (k64[s + 3] < c3) ? k64[s + 3] : c3;
        }
        c0 = (c1 < c0) ? c1 : c0;
        c2 = (c3 < c2) ? c3 : c2;
        unsigned long long lm = (c2 < c0) ? c2 : c0;
        #pragma unroll
        for (int off = 1; off < 64; off <<= 1) {
            unsigned long long o = __shfl_xor(lm, off);
            lm = (o < lm) ? o : lm;
        }
        unsigned int j = (unsigned int)lm;
        if ((j & 63u) == (unsigned int)lane) {
            int slot = (int)(j >> 6);
            #pragma unroll
            for (int s = 0; s < 32; s++)
                if (s == slot) k64[s] |= 0xFFFFFFFF00000000ull;
        }
        if (lane == k) myj = j;
    }
    size_t qb = (size_t)q * KNB;
    if (lane < KNB) {
        idx_out[qb + lane] = (int)myj;
        eidx_out[qb + lane] = (float)myj;
    }
}

// ---------------------------------------------------------------------------
// K3: TU = Vb(8192x128) @ Wt^T  -> bf16 TU (8192x800).  One wave per 16x16
// tile, K=128 via 4x mfma_f32_16x16x32_bf16.
// ---------------------------------------------------------------------------
__global__ __launch_bounds__(256) void gemm_kernel(
    const unsigned short* __restrict__ Vb, const unsigned short* __restrict__ Wt,
    unsigned short* __restrict__ TU) {
    int wid = threadIdx.x >> 6, lane = threadIdx.x & 63;
    int tile = blockIdx.x * 4 + wid;       // 25600 tiles
    int tm = tile / 50, tn = tile % 50;
    int r16 = lane & 15, quad = lane >> 4;

    const unsigned short* Abase = Vb + (size_t)(tm * 16 + r16) * IND + quad * 8;
    const unsigned short* Bbase = Wt + (size_t)(tn * 16 + r16) * IND + quad * 8;

    f32x4 acc = {0.f, 0.f, 0.f, 0.f};
    #pragma unroll
    for (int kk = 0; kk < IND; kk += 32) {
        short8 a = *(const short8*)(Abase + kk);
        short8 b = *(const short8*)(Bbase + kk);
        acc = __builtin_amdgcn_mfma_f32_16x16x32_bf16(a, b, acc, 0, 0, 0);
    }
    int col = lane & 15;
    #pragma unroll
    for (int r = 0; r < 4; r++) {
        int m = tm * 16 + quad * 4 + r;
        TU[(size_t)m * NGEMM + tn * 16 + col] = f2b(acc[r]);
    }
}

// ---------------------------------------------------------------------------
// K4: epilogue.  TWO waves per (b,l): wave-half h covers k in [15h, 15h+15).
// Per group of 3 k's all 6 gather loads issue before any store (MLP=6);
// idx row preloaded once and distributed via __shfl (no per-iter idx load).
// Output is write-once streaming -> nontemporal stores keep L2 free for the
// heavily-reused TU rows (each U row gathered ~30x).
// ---------------------------------------------------------------------------
__device__ __forceinline__ f32x4 comb(const float* tt, ushort4 u) {
    f32x4 o;
    o.x = tt[0] + b2f(u.x);
    o.y = tt[1] + b2f(u.y);
    o.z = tt[2] + b2f(u.z);
    o.w = tt[3] + b2f(u.w);
    return o;
}

__global__ __launch_bounds__(256) void epi_kernel(
    const unsigned short* __restrict__ TU, const int* __restrict__ idx,
    const float* __restrict__ bias, float* __restrict__ out) {
    int t = threadIdx.x;
    int wid = t >> 6, lane = t & 63;
    int q = blockIdx.x * 2 + (wid >> 1);   // 2 queries per block
    int half = wid & 1;                    // which 15 of the 30 neighbors
    int b = q >> 11;

    const int* mi = idx + (size_t)q * KNB;
    int jv = (lane < KNB) ? mi[lane] : 0;  // one coalesced preload of all idx
    int i0 = __shfl(jv, 0);
    size_t rowbase = (size_t)(b * LL);
    size_t rowT = (rowbase + i0) * NGEMM;

    float t0[4], t1[4];
    {
        ushort4 u = *(const ushort4*)(TU + rowT + lane * 4);
        float4 bb = *(const float4*)(bias + lane * 4);
        t0[0] = b2f(u.x) + bb.x;
        t0[1] = b2f(u.y) + bb.y;
        t0[2] = b2f(u.z) + bb.z;
        t0[3] = b2f(u.w) + bb.w;
    }
    bool has2 = lane < 36;
    int c2 = lane + 64;
    if (has2) {
        ushort4 u = *(const ushort4*)(TU + rowT + c2 * 4);
        float4 bb = *(const float4*)(bias + c2 * 4);
        t1[0] = b2f(u.x) + bb.x;
        t1[1] = b2f(u.y) + bb.y;
        t1[2] = b2f(u.z) + bb.z;
        t1[3] = b2f(u.w) + bb.w;
    }

    size_t outbase = (size_t)q * KNB * OUTD;
    int kb = half * 15;
    for (int g = 0; g < 5; g++) {
        int k0 = kb + g * 3;
        int j0 = __shfl(jv, k0);
        int j1 = __shfl(jv, k0 + 1);
        int j2 = __shfl(jv, k0 + 2);
        const unsigned short* r0 = TU + (rowbase + j0) * NGEMM + OUTD;
        const unsigned short* r1 = TU + (rowbase + j1) * NGEMM + OUTD;
        const unsigned short* r2 = TU + (rowbase + j2) * NGEMM + OUTD;
        // issue all gathers before any use
        ushort4 a0 = *(const ushort4*)(r0 + lane * 4);
        ushort4 a1 = *(const ushort4*)(r1 + lane * 4);
        ushort4 a2 = *(const ushort4*)(r2 + lane * 4);
        ushort4 b0, b1, b2;
        if (has2) {
            b0 = *(const ushort4*)(r0 + c2 * 4);
            b1 = *(const ushort4*)(r1 + c2 * 4);
            b2 = *(const ushort4*)(r2 + c2 * 4);
        }
        float* o0 = out + outbase + (size_t)(k0    ) * OUTD;
        float* o1 = out + outbase + (size_t)(k0 + 1) * OUTD;
        float* o2 = out + outbase + (size_t)(k0 + 2) * OUTD;
        __builtin_nontemporal_store(comb(t0, a0), (f32x4*)(o0 + lane * 4));
        __builtin_nontemporal_store(comb(t0, a1), (f32x4*)(o1 + lane * 4));
        __builtin_nontemporal_store(comb(t0, a2), (f32x4*)(o2 + lane * 4));
        if (has2) {
            __builtin_nontemporal_store(comb(t1, b0), (f32x4*)(o0 + c2 * 4));
            __builtin_nontemporal_store(comb(t1, b1), (f32x4*)(o1 + c2 * 4));
            __builtin_nontemporal_store(comb(t1, b2), (f32x4*)(o2 + c2 * 4));
        }
    }
}

extern "C" void kernel_launch(void* const* d_in, const int* in_sizes, int n_in,
                              void* d_out, int out_size, void* d_ws, size_t ws_size,
                              hipStream_t stream) {
    const float* X    = (const float*)d_in[0];
    const float* mask = (const float*)d_in[1];
    const float* V    = (const float*)d_in[2];
    const float* W    = (const float*)d_in[3];
    const float* bias = (const float*)d_in[4];
    float* out = (float*)d_out;

    char* ws = (char*)d_ws;
    unsigned short* Vb  = (unsigned short*)(ws);                 // 2,097,152 B
    unsigned short* Wt  = (unsigned short*)(ws + 2097152);       //   204,800 B
    float*          Xpl = (float*)(ws + 2301952);                //    98,304 B
    int*            idx = (int*)(ws + 2400256);                  //   983,040 B
    unsigned short* TU  = (unsigned short*)(ws + 3383296);       // 13,107,200 B
    // total ws use: ~15.7 MB

    convert_kernel<<<1520, 256, 0, stream>>>(V, W, X, Vb, Wt, Xpl);
    knn_kernel<<<NQ / 4, 256, 0, stream>>>(Xpl, mask, idx, out + OUT_EIDX_OFF);
    gemm_kernel<<<6400, 256, 0, stream>>>(Vb, Wt, TU);
    epi_kernel<<<NQ / 2, 256, 0, stream>>>(TU, idx, bias, out);
}